// Round 1
// baseline (338.850 us; speedup 1.0000x reference)
//
#include <hip/hip_runtime.h>
#include <math.h>

#define D 2048
#define E 64
#define TOKENS_PER_BLOCK 64
#define WAVES_PER_BLOCK 8
#define THREADS (WAVES_PER_BLOCK * 64)
#define KCHUNK (D / WAVES_PER_BLOCK)   // 256 d-values per wave

// One block = 64 tokens. 8 waves split the K dimension (256 d each).
// lane = token; each lane holds all 64 expert accumulators in VGPRs.
// W rows are wave-uniform -> scalar (s_load) operands for v_fmac.
__global__ __launch_bounds__(THREADS, 2)
void gating_kernel(const float* __restrict__ x,
                   const float* __restrict__ W,
                   const float* __restrict__ b,
                   float* __restrict__ out)
{
    const int lane = threadIdx.x & 63;
    // readfirstlane so the compiler's uniformity analysis sees wave id as
    // uniform -> W addresses become scalar loads (s_load), not per-lane VMEM.
    const int wave = __builtin_amdgcn_readfirstlane(threadIdx.x >> 6);
    const int tokBase = blockIdx.x * TOKENS_PER_BLOCK;
    const int token = tokBase + lane;

    float acc[E];
#pragma unroll
    for (int e = 0; e < E; ++e) acc[e] = 0.0f;

    const float4* xp = (const float4*)(x + (size_t)token * D + (size_t)wave * KCHUNK);
    const float* Wp = W + (size_t)wave * KCHUNK * E;

    // 2-deep prefetch pipeline on the per-lane x stream.
    float4 buf0 = xp[0];
    float4 buf1 = xp[1];
#pragma unroll 1
    for (int i = 0; i < KCHUNK / 4; ++i) {
        float4 cur = buf0;
        buf0 = buf1;
        int ip = i + 2 < KCHUNK / 4 ? i + 2 : KCHUNK / 4 - 1;
        buf1 = xp[ip];

        const float* wrow = Wp + i * 4 * E;   // uniform address
#pragma unroll
        for (int j = 0; j < 4; ++j) {
            const float xj = j == 0 ? cur.x : (j == 1 ? cur.y : (j == 2 ? cur.z : cur.w));
#pragma unroll
            for (int e = 0; e < E; ++e) {
                acc[e] = fmaf(xj, wrow[j * E + e], acc[e]);
            }
        }
    }

    // Cross-wave K-reduction in LDS. Row stride 66 -> 2-way bank aliasing (free).
    __shared__ float red[TOKENS_PER_BLOCK][E + 2];
    for (int t = threadIdx.x; t < TOKENS_PER_BLOCK * (E + 2); t += THREADS)
        ((float*)red)[t] = 0.0f;
    __syncthreads();

#pragma unroll
    for (int e = 0; e < E; ++e)
        atomicAdd(&red[lane][e], acc[e]);
    __syncthreads();

    __shared__ int   s_i1[TOKENS_PER_BLOCK], s_i2[TOKENS_PER_BLOCK];
    __shared__ float s_w1[TOKENS_PER_BLOCK], s_w2[TOKENS_PER_BLOCK];

    if (wave == 0) {
        // lane = token_local: scan 64 experts for top-2 (strict > keeps the
        // lowest index on ties, matching jax.lax.top_k).
        float m1 = -INFINITY, m2 = -INFINITY;
        int i1 = 0, i2 = 0;
#pragma unroll
        for (int e = 0; e < E; ++e) {
            float v = red[lane][e] + b[e];
            if (v > m1) { m2 = m1; i2 = i1; m1 = v; i1 = e; }
            else if (v > m2) { m2 = v; i2 = e; }
        }
        // softmax over {m1, m2}: stable since m2 - m1 <= 0
        float p = 1.0f / (1.0f + expf(m2 - m1));
        s_i1[lane] = i1; s_i2[lane] = i2;
        s_w1[lane] = p;  s_w2[lane] = 1.0f - p;
    }
    __syncthreads();

    // Coalesced scatter-write of the 64x64 output tile (mostly zeros).
    float* op = out + (size_t)tokBase * E;
#pragma unroll
    for (int r = 0; r < (TOKENS_PER_BLOCK * E) / THREADS; ++r) {
        int j = r * THREADS + threadIdx.x;
        int tl = j >> 6;   // token_local (wave-uniform per iteration)
        int e = j & 63;
        float v = 0.0f;
        if (e == s_i1[tl]) v = s_w1[tl];
        else if (e == s_i2[tl]) v = s_w2[tl];
        op[j] = v;
    }
}

extern "C" void kernel_launch(void* const* d_in, const int* in_sizes, int n_in,
                              void* d_out, int out_size, void* d_ws, size_t ws_size,
                              hipStream_t stream) {
    const float* x = (const float*)d_in[0];
    const float* W = (const float*)d_in[1];
    const float* b = (const float*)d_in[2];
    float* out = (float*)d_out;

    const int tokens = in_sizes[0] / D;                    // 16384
    const int blocks = tokens / TOKENS_PER_BLOCK;          // 256

    gating_kernel<<<blocks, THREADS, 0, stream>>>(x, W, b, out);
}